// Round 5
// baseline (132.749 us; speedup 1.0000x reference)
//
#include <hip/hip_runtime.h>
#include <hip/hip_bf16.h>

// Problem constants
#define N_   4
#define C_   64
#define CI_  16
#define H_   96
#define W__  96
#define PS_  7
#define S0_  4
#define WS_  9
#define K_   32
#define WH_  4      // WS/2
#define PP_  3      // PS/2
#define nH_  24     // H/S0
#define NQ_  576    // nH*nH
#define D_   784    // CI*PS*PS
#define HW_  9216   // H*W

#define PLS  226    // P LDS plane stride (226 % 32 == 2 -> 2-way-free banks)
#define QLS  52     // Q LDS channel stride (float4-aligned)
#define GLS  16     // G LDS layout [px(225)][c(16)] bf16

__device__ __forceinline__ int rf(int v) {
    v = v < 0 ? -v : v;
    return v > H_ - 1 ? 2 * (H_ - 1) - v : v;
}

// ---------------------------------------------------------------------------
// K1: fused 1x1 convs. Thread = (pixel, array, 8-output group). All 64 vid
// channel loads staged to registers FIRST (64-deep memory-level parallelism),
// then 512 FMAs with block-uniform s_load weights. 864 blocks x 256.
// ---------------------------------------------------------------------------
__global__ __launch_bounds__(256) void conv_kernel(
    const float* __restrict__ vid,
    const float* __restrict__ tw, const float* __restrict__ tb,
    const float* __restrict__ pw, const float* __restrict__ pb,
    const float* __restrict__ gw, const float* __restrict__ gb,
    float* __restrict__ theta, float* __restrict__ phi, float* __restrict__ g)
{
    int b = blockIdx.x;
    int pbk = b % 144;            // 144 pixel-blocks of 256 pixels
    int t2  = b / 144;
    int og  = t2 & 1;             // output half
    int arr = t2 >> 1;            // 0=theta 1=phi 2=g
    const float* wsel = arr == 0 ? tw : (arr == 1 ? pw : gw);
    const float* bsel = arr == 0 ? tb : (arr == 1 ? pb : gb);
    float*       dsel = arr == 0 ? theta : (arr == 1 ? phi : g);

    int idx = pbk * 256 + threadIdx.x;
    int n = idx / HW_, pix = idx % HW_;
    const float* vp = vid + (size_t)n * C_ * HW_ + pix;
    const float* wp = wsel + og * 8 * C_;

    float v[64];
#pragma unroll
    for (int c = 0; c < 64; c++) v[c] = vp[c * HW_];

    float acc[8];
#pragma unroll
    for (int o = 0; o < 8; o++) acc[o] = 0.f;
#pragma unroll
    for (int o = 0; o < 8; o++) {
#pragma unroll
        for (int c = 0; c < 64; c += 4) {
            float4 w4 = *(const float4*)&wp[o * C_ + c];   // uniform -> s_load
            acc[o] += w4.x * v[c] + w4.y * v[c + 1] + w4.z * v[c + 2] + w4.w * v[c + 3];
        }
    }

    size_t ob = (size_t)idx * CI_ + og * 8;
    *(float4*)&dsel[ob + 0] = make_float4(acc[0] + bsel[og * 8 + 0],
                                          acc[1] + bsel[og * 8 + 1],
                                          acc[2] + bsel[og * 8 + 2],
                                          acc[3] + bsel[og * 8 + 3]);
    *(float4*)&dsel[ob + 4] = make_float4(acc[4] + bsel[og * 8 + 4],
                                          acc[5] + bsel[og * 8 + 5],
                                          acc[6] + bsel[og * 8 + 6],
                                          acc[7] + bsel[og * 8 + 7]);
}

// ---------------------------------------------------------------------------
// K2: per (n,q), 256 threads. LDS ~25.9 KB -> ~5-6 blocks/CU.
//  A: stage Q (fp32) + phi region (fp32) + g region (bf16, smooth path only).
//  B: 144 lanes (c,cj) sliding correlation; cross-c __shfl_xor reduce -> dist.
//  C: window-mapped dists, stable top-32 rank, ballot-based positions,
//     register esum, weighted bf16-G sum.
// ---------------------------------------------------------------------------
__global__ __launch_bounds__(256) void attn_kernel(
    const float* __restrict__ theta, const float* __restrict__ phi,
    const float* __restrict__ g, const int* __restrict__ flows,
    float* __restrict__ outp)
{
    __shared__ float Ql[CI_ * QLS];           // 3328 B
    __shared__ float Pl[CI_ * PLS];           // 14464 B
    __shared__ __hip_bfloat16 Gl[225 * GLS];  // 7200 B
    __shared__ float dist[81];                // indexed (cj*9+ci)
    __shared__ float distW[81];               // indexed by window
    __shared__ float wlist[K_];
    __shared__ int   olist[K_];
    __shared__ float dmin_s;
    __shared__ int   cnt0_s;

    int tid = threadIdx.x;
    int bq  = blockIdx.x;
    int n = bq / NQ_, q0 = bq % NQ_;
    int qi = q0 / nH_, qj = q0 % nH_;
    int qci = qi * S0_, qcj = qj * S0_;

    int f0 = flows[((n * 2 + 0) * H_ + qci) * W__ + qcj];
    int f1 = flows[((n * 2 + 1) * H_ + qci) * W__ + qcj];
    int bi = qci + f0, bj = qcj + f1;
    int loi = min(max(bi - WH_, 0), H_ - 1);
    int loj = min(max(bj - WH_, 0), W__ - 1);

    const float* thn = theta + (size_t)n * HW_ * CI_;
    const float* phn = phi   + (size_t)n * HW_ * CI_;
    const float* gn  = g     + (size_t)n * HW_ * CI_;

    // ---- Phase A: staging ----
    if (tid < 196) {
        int px = tid >> 2, cg = (tid & 3) * 4;
        int r = px / 7, s = px % 7;
        size_t gb = ((size_t)(rf(qci + r - PP_) * W__ + rf(qcj + s - PP_))) * CI_ + cg;
        float4 v = *(const float4*)&thn[gb];
        Ql[(cg + 0) * QLS + px] = v.x;
        Ql[(cg + 1) * QLS + px] = v.y;
        Ql[(cg + 2) * QLS + px] = v.z;
        Ql[(cg + 3) * QLS + px] = v.w;
    }
    for (int i = tid; i < 225 * 4; i += 256) {
        int px = i >> 2, cg = (i & 3) * 4;
        int r = px / 15, s = px % 15;
        size_t gb = ((size_t)(rf(loi + r - PP_) * W__ + rf(loj + s - PP_))) * CI_ + cg;
        float4 pv = *(const float4*)&phn[gb];
        float4 gv = *(const float4*)&gn[gb];
        Pl[(cg + 0) * PLS + px] = pv.x;
        Pl[(cg + 1) * PLS + px] = pv.y;
        Pl[(cg + 2) * PLS + px] = pv.z;
        Pl[(cg + 3) * PLS + px] = pv.w;
        Gl[px * GLS + cg + 0] = __float2bfloat16(gv.x);
        Gl[px * GLS + cg + 1] = __float2bfloat16(gv.y);
        Gl[px * GLS + cg + 2] = __float2bfloat16(gv.z);
        Gl[px * GLS + cg + 3] = __float2bfloat16(gv.w);
    }
    __syncthreads();

    // ---- Phase B: per-(c,cj) sliding correlation + cross-c shuffle reduce ----
    if (tid < 144) {
        int c  = tid & 15;
        int cj = tid >> 4;                 // 0..8
        float qr[49];
#pragma unroll
        for (int i2 = 0; i2 < 12; i2++) {
            float4 t4 = *(const float4*)&Ql[c * QLS + i2 * 4];
            qr[i2 * 4 + 0] = t4.x; qr[i2 * 4 + 1] = t4.y;
            qr[i2 * 4 + 2] = t4.z; qr[i2 * 4 + 3] = t4.w;
        }
        qr[48] = Ql[c * QLS + 48];

        float corr[9], sqv[9];
#pragma unroll
        for (int i2 = 0; i2 < 9; i2++) { corr[i2] = 0.f; sqv[i2] = 0.f; }

        const float* Pb = &Pl[c * PLS + cj];
#pragma unroll
        for (int y = 0; y < 15; y++) {
            float seg[7];
#pragma unroll
            for (int s = 0; s < 7; s++) seg[s] = Pb[y * 15 + s];
            float s2 = 0.f;
#pragma unroll
            for (int s = 0; s < 7; s++) s2 += seg[s] * seg[s];
#pragma unroll
            for (int ci = 0; ci < 9; ci++) {
                if (y - ci >= 0 && y - ci < 7) {       // compile-time per (y,ci)
                    const int r = y - ci;
                    float t = 0.f;
#pragma unroll
                    for (int s = 0; s < 7; s++) t += qr[r * 7 + s] * seg[s];
                    corr[ci] += t;
                    sqv[ci]  += s2;
                }
            }
        }
        // reduce across the 16 c-lanes (butterfly); lane c==ci writes
#pragma unroll
        for (int ci = 0; ci < 9; ci++) {
            float v2 = sqv[ci] - 2.f * corr[ci];
#pragma unroll
            for (int m2 = 1; m2 < 16; m2 <<= 1) v2 += __shfl_xor(v2, m2, 16);
            if (c == ci) dist[cj * 9 + ci] = v2;
        }
    }
    __syncthreads();

    // ---- Phase C: window-mapped dist, rank, ballot position, softmax ----
    float d = 0.f;
    int cil = 0, cjl = 0;
    if (tid < 81) {
        int wi = tid / WS_, wj = tid % WS_;
        cil = min(max(bi + wi - WH_, 0), H_ - 1) - loi;
        cjl = min(max(bj + wj - WH_, 0), W__ - 1) - loj;
        d = dist[cjl * 9 + cil];
        distW[tid] = d;
    }
    __syncthreads();

    bool sel = false;
    if (tid < 81) {
        int rank = 0;
        for (int j = 0; j < 81; j++) {
            float dj = distW[j];
            rank += (dj < d) || (dj == d && j < tid);
        }
        sel = rank < K_;
        if (rank == 0) dmin_s = d;
    }
    unsigned long long m = __ballot(sel);
    if (tid == 0) cnt0_s = __popcll(m);
    __syncthreads();

    if (sel) {
        unsigned long long lt = ((unsigned long long)1 << (tid & 63)) - 1;
        int pos = __popcll(m & lt) + (tid >= 64 ? cnt0_s : 0);
        float e = expf(10.f * (dmin_s - d));
        wlist[pos] = e;
        olist[pos] = cil * 15 + cjl;
    }
    __syncthreads();

    // ---- Phase C3: weighted G-patch sum (register esum) ----
    float wreg[K_];
    int   oreg[K_];
    float esum = 0.f;
#pragma unroll
    for (int k = 0; k < K_; k++) {
        wreg[k] = wlist[k];
        esum += wreg[k];
        oreg[k] = olist[k] * GLS;
    }
    float inv_es = 1.f / esum;
#pragma unroll
    for (int k = 0; k < K_; k++) wreg[k] *= inv_es;

    float* op = outp + (size_t)bq * D_;
    for (int dI = tid; dI < D_; dI += 256) {
        int rs = dI >> 4, c = dI & 15;
        int r = rs / 7, s = rs % 7;
        int base2 = (r * 15 + s) * GLS + c;
        float acc = 0.f;
#pragma unroll
        for (int k = 0; k < K_; k++)
            acc += wreg[k] * __bfloat162float(Gl[oreg[k] + base2]);
        op[dI] = acc;
    }
}

// ---------------------------------------------------------------------------
// K3: grid (144, 8) x 256. Thread = pixel; blockIdx.y = 8-output group
// (uniform -> s_load weights). No LDS, no syncs. Gather <=4 contributions
// (4x float4 each, contiguous), analytic count, conv + bias + residual.
// ---------------------------------------------------------------------------
__global__ __launch_bounds__(256) void output_kernel(
    const float* __restrict__ vid, const float* __restrict__ outp,
    const float* __restrict__ ww, const float* __restrict__ wb,
    float* __restrict__ out)
{
    int tid = threadIdx.x;
    int og  = blockIdx.y;
    int idx = blockIdx.x * 256 + tid;
    int n = idx / HW_, pix = idx % HW_;
    int y = pix / W__, x = pix % W__;
    int tlo_i = y >> 2, tlo_j = x >> 2;
    int thi_i = min(nH_ - 1, (y + PP_) >> 2);
    int thi_j = min(nH_ - 1, (x + PP_) >> 2);
    int ni = thi_i - tlo_i + 1;
    int nj = thi_j - tlo_j + 1;
    float inv = 1.f / (float)(ni * nj);

    float agg[CI_];
#pragma unroll
    for (int c = 0; c < CI_; c++) agg[c] = 0.f;

#pragma unroll
    for (int cb = 0; cb < 4; cb++) {
        int qi = tlo_i + (cb >> 1);
        int qj = tlo_j + (cb & 1);
        if (qi <= thi_i && qj <= thi_j) {
            int a  = y + PP_ - S0_ * qi;          // 0..6
            int bb = x + PP_ - S0_ * qj;          // 0..6
            const float* op = outp +
                (((size_t)n * NQ_ + qi * nH_ + qj) * 49 + a * 7 + bb) * CI_;
            float4 r0 = *(const float4*)&op[0];
            float4 r1 = *(const float4*)&op[4];
            float4 r2 = *(const float4*)&op[8];
            float4 r3 = *(const float4*)&op[12];
            agg[0] += r0.x; agg[1] += r0.y; agg[2]  += r0.z; agg[3]  += r0.w;
            agg[4] += r1.x; agg[5] += r1.y; agg[6]  += r1.z; agg[7]  += r1.w;
            agg[8] += r2.x; agg[9] += r2.y; agg[10] += r2.z; agg[11] += r2.w;
            agg[12] += r3.x; agg[13] += r3.y; agg[14] += r3.z; agg[15] += r3.w;
        }
    }
#pragma unroll
    for (int c = 0; c < CI_; c++) agg[c] *= inv;

    const float* vp  = vid + (size_t)n * C_ * HW_ + pix;
    float*       op2 = out + (size_t)n * C_ * HW_ + pix;
#pragma unroll
    for (int oo = 0; oo < 8; oo++) {
        int co = og * 8 + oo;                       // uniform
        float4 w0 = *(const float4*)&ww[co * CI_ + 0];
        float4 w1 = *(const float4*)&ww[co * CI_ + 4];
        float4 w2 = *(const float4*)&ww[co * CI_ + 8];
        float4 w3 = *(const float4*)&ww[co * CI_ + 12];
        float s = wb[co];
        s += w0.x * agg[0]  + w0.y * agg[1]  + w0.z * agg[2]  + w0.w * agg[3];
        s += w1.x * agg[4]  + w1.y * agg[5]  + w1.z * agg[6]  + w1.w * agg[7];
        s += w2.x * agg[8]  + w2.y * agg[9]  + w2.z * agg[10] + w2.w * agg[11];
        s += w3.x * agg[12] + w3.y * agg[13] + w3.z * agg[14] + w3.w * agg[15];
        op2[(size_t)co * HW_] = vp[(size_t)co * HW_] + s;
    }
}

// ---------------------------------------------------------------------------
extern "C" void kernel_launch(void* const* d_in, const int* in_sizes, int n_in,
                              void* d_out, int out_size, void* d_ws, size_t ws_size,
                              hipStream_t stream) {
    const float* vid   = (const float*)d_in[0];
    const int*   flows = (const int*)  d_in[1];
    const float* tw    = (const float*)d_in[2];
    const float* tb    = (const float*)d_in[3];
    const float* pw    = (const float*)d_in[4];
    const float* pb    = (const float*)d_in[5];
    const float* gw    = (const float*)d_in[6];
    const float* gb    = (const float*)d_in[7];
    const float* ww    = (const float*)d_in[8];
    const float* wb    = (const float*)d_in[9];
    float* out = (float*)d_out;

    float* ws = (float*)d_ws;
    const size_t fsz = (size_t)N_ * HW_ * CI_;          // 589,824 floats each
    float* theta = ws;
    float* phi   = ws + fsz;
    float* g     = ws + 2 * fsz;
    float* outp  = ws + 3 * fsz;                        // N*NQ*784 floats

    conv_kernel<<<864, 256, 0, stream>>>(
        vid, tw, tb, pw, pb, gw, gb, theta, phi, g);
    attn_kernel<<<N_ * NQ_, 256, 0, stream>>>(theta, phi, g, flows, outp);
    output_kernel<<<dim3(144, 8), 256, 0, stream>>>(vid, outp, ww, wb, out);
}